// Round 2
// baseline (1878.848 us; speedup 1.0000x reference)
//
#include <hip/hip_runtime.h>

#define E_TOT   400000
#define N_NODES 50000
#define H_DIM   128
#define D_DIM   256
#define TE      128                 // edges per block
#define NBLK    (E_TOT / TE)        // 3125

typedef _Float16 f16x8 __attribute__((ext_vector_type(8)));
typedef float    f32x4 __attribute__((ext_vector_type(4)));
typedef float    f32x16 __attribute__((ext_vector_type(16)));

// swizzled f16 index into the [128][256] LDS tile: XOR row bits into the
// 16B-chunk bits of the column so stride-512B column reads spread across banks
__device__ __forceinline__ int swz(int row, int col) {
    return row * 256 + (col ^ ((row & 7) << 3));
}

__device__ __forceinline__ f32x16 zero16() {
    f32x16 z = {0.f,0.f,0.f,0.f,0.f,0.f,0.f,0.f,0.f,0.f,0.f,0.f,0.f,0.f,0.f,0.f};
    return z;
}

// ---------------------------------------------------------------------------
// Prep: repack w_up [128][256] and Ws [3][256][256] (fp32, row-major [in][out])
// into fragment-ordered f16 so a B-fragment (16k x 32col for 32x32x16 MFMA) is
// one contiguous 1 KB chunk: elem(lane,j) = W[kb*16 + 8*(lane>>5)+j][nb*32+(lane&31)]
// Layout in ws (f16 units):
//   [0 .. 32768)        w_up frags: frag = nb*8 + kb   (nb 0..7, kb 0..7)
//   [32768 .. 229376)   Ws frags:   layer*65536 + (nb*16+kb)*512
// ---------------------------------------------------------------------------
__global__ void prep_weights(const float* __restrict__ w_up,
                             const float* __restrict__ Ws,
                             _Float16* __restrict__ wf)
{
    int t = blockIdx.x * 256 + threadIdx.x;    // 0 .. 229375
    int j    = t & 7;
    int lane = (t >> 3) & 63;
    int frag = t >> 9;
    int khalf = (lane >> 5) << 3;              // 0 or 8
    int col31 = lane & 31;
    float v;
    if (frag < 64) {                           // w_up: K=128 -> kb 0..7
        int nb = frag >> 3, kb = frag & 7;
        int k   = kb * 16 + khalf + j;
        int col = nb * 32 + col31;
        v = w_up[k * 256 + col];
    } else {                                   // Ws: K=256 -> kb 0..15
        int f2 = frag - 64;
        int layer = f2 >> 7;
        int fl = f2 & 127;
        int nb = fl >> 4, kb = fl & 15;
        int k   = kb * 16 + khalf + j;
        int col = nb * 32 + col31;
        v = Ws[layer * 65536 + k * 256 + col];
    }
    wf[t] = (_Float16)v;
}

// ---------------------------------------------------------------------------
// Fused: h = (rbf@w_rbf)*x ; atomic scatter into x_spe ; f16 MFMA tower
//   GEMM1: [128,128]@[128,256] ; 3x silu([128,256]@[256,256]+b) ; dot w_out
// 4 waves: wave = (rs,cs) owns rows rs*64..+64, cols cs*128..+128
//   acc = 2 row-frags x 4 col-frags of 32x32 (16 f32/lane each) = 128 VGPR
// ---------------------------------------------------------------------------
__global__ __launch_bounds__(256, 2)
void fused_main(const float* __restrict__ x,
                const float* __restrict__ rbf,
                const int*   __restrict__ nidx,
                const float* __restrict__ w_rbf,
                const float* __restrict__ bs,
                const float* __restrict__ w_out,
                const _Float16* __restrict__ wf,
                float* __restrict__ xspe,
                float* __restrict__ out)
{
    __shared__ __align__(16) _Float16 tbuf[TE * 256];   // 64 KB
    const int tid = threadIdx.x;
    const int e0  = blockIdx.x * TE;

    // ---------------- stage 1: h + scatter + f16 tile ----------------
    {
        const int cg = tid & 15;        // col group: cols 8*cg..+7
        const int eg = tid >> 4;        // edge group: edges 8*eg..+7
        const int c0 = cg << 3;
        float wr[6][8];                 // w_rbf slice in registers
        #pragma unroll
        for (int r = 0; r < 6; ++r)
            #pragma unroll
            for (int c = 0; c < 8; ++c)
                wr[r][c] = w_rbf[r * 128 + c0 + c];

        #pragma unroll
        for (int ee = 0; ee < 8; ++ee) {
            int el = eg * 8 + ee;
            int e  = e0 + el;
            float rb[6];
            #pragma unroll
            for (int r = 0; r < 6; ++r) rb[r] = rbf[(size_t)e * 6 + r];
            int node = nidx[e];
            float* xrow = xspe + (size_t)node * 128 + c0;
            f32x4 xv0 = *(const f32x4*)(x + (size_t)e * 128 + c0);
            f32x4 xv1 = *(const f32x4*)(x + (size_t)e * 128 + c0 + 4);
            f16x8 hv;
            #pragma unroll
            for (int c = 0; c < 8; ++c) {
                float s = 0.f;
                #pragma unroll
                for (int r = 0; r < 6; ++r) s += rb[r] * wr[r][c];
                float xvv = (c < 4) ? xv0[c] : xv1[c - 4];
                float h = s * xvv;
                atomicAdd(xrow + c, h);
                hv[c] = (_Float16)h;
            }
            *(f16x8*)&tbuf[swz(el, c0)] = hv;   // cols c0..c0+7 (8-aligned, swz-safe)
        }
    }
    __syncthreads();

    const int l    = tid & 63;
    const int w    = tid >> 6;
    const int rs   = w >> 1;            // row half 0/1
    const int cs   = w & 1;             // col half 0/1
    const int l31  = l & 31;
    const int lh   = l >> 5;
    const int khalf = lh << 3;

    const f16x8* __restrict__ wupf = (const f16x8*)wf;          // 64 frags
    const f16x8* __restrict__ wlf  = ((const f16x8*)wf) + 4096; // layer frags

    f32x16 acc[2][4];

    // ---------------- GEMM1: t1 = h @ w_up (K=128, no bias/act) ----------------
    #pragma unroll
    for (int rf = 0; rf < 2; ++rf)
        #pragma unroll
        for (int nf = 0; nf < 4; ++nf) acc[rf][nf] = zero16();

    for (int kb = 0; kb < 8; ++kb) {
        int k0 = kb * 16 + khalf;
        f16x8 a0 = *(const f16x8*)&tbuf[swz(rs * 64 +  0 + l31, k0)];
        f16x8 a1 = *(const f16x8*)&tbuf[swz(rs * 64 + 32 + l31, k0)];
        f16x8 b[4];
        #pragma unroll
        for (int nf = 0; nf < 4; ++nf) {
            int nb = cs * 4 + nf;
            b[nf] = wupf[(nb * 8 + kb) * 64 + l];
        }
        #pragma unroll
        for (int nf = 0; nf < 4; ++nf) {
            acc[0][nf] = __builtin_amdgcn_mfma_f32_32x32x16_f16(a0, b[nf], acc[0][nf], 0, 0, 0);
            acc[1][nf] = __builtin_amdgcn_mfma_f32_32x32x16_f16(a1, b[nf], acc[1][nf], 0, 0, 0);
        }
    }
    __syncthreads();
    #pragma unroll
    for (int rf = 0; rf < 2; ++rf)
        #pragma unroll
        for (int nf = 0; nf < 4; ++nf) {
            int colg = cs * 128 + nf * 32 + l31;
            #pragma unroll
            for (int r = 0; r < 16; ++r) {
                int rowl = (r & 3) + 8 * (r >> 2) + 4 * lh;   // C/D layout m74/m101
                int row  = rs * 64 + rf * 32 + rowl;
                tbuf[swz(row, colg)] = (_Float16)acc[rf][nf][r];
            }
        }
    __syncthreads();

    // ---------------- 3x: t = silu(t @ W + b), K=256 ----------------
    for (int layer = 0; layer < 3; ++layer) {
        const f16x8* wl = wlf + layer * 8192;
        float bias[4];
        #pragma unroll
        for (int nf = 0; nf < 4; ++nf)
            bias[nf] = bs[layer * 256 + cs * 128 + nf * 32 + l31];
        #pragma unroll
        for (int rf = 0; rf < 2; ++rf)
            #pragma unroll
            for (int nf = 0; nf < 4; ++nf) acc[rf][nf] = zero16();

        for (int kb = 0; kb < 16; ++kb) {
            int k0 = kb * 16 + khalf;
            f16x8 a0 = *(const f16x8*)&tbuf[swz(rs * 64 +  0 + l31, k0)];
            f16x8 a1 = *(const f16x8*)&tbuf[swz(rs * 64 + 32 + l31, k0)];
            f16x8 b[4];
            #pragma unroll
            for (int nf = 0; nf < 4; ++nf) {
                int nb = cs * 4 + nf;
                b[nf] = wl[(nb * 16 + kb) * 64 + l];
            }
            #pragma unroll
            for (int nf = 0; nf < 4; ++nf) {
                acc[0][nf] = __builtin_amdgcn_mfma_f32_32x32x16_f16(a0, b[nf], acc[0][nf], 0, 0, 0);
                acc[1][nf] = __builtin_amdgcn_mfma_f32_32x32x16_f16(a1, b[nf], acc[1][nf], 0, 0, 0);
            }
        }
        __syncthreads();
        #pragma unroll
        for (int rf = 0; rf < 2; ++rf)
            #pragma unroll
            for (int nf = 0; nf < 4; ++nf) {
                int colg = cs * 128 + nf * 32 + l31;
                #pragma unroll
                for (int r = 0; r < 16; ++r) {
                    int rowl = (r & 3) + 8 * (r >> 2) + 4 * lh;
                    int row  = rs * 64 + rf * 32 + rowl;
                    float v = acc[rf][nf][r] + bias[nf];
                    float sg = __builtin_amdgcn_rcpf(1.0f + __expf(-v));
                    tbuf[swz(row, colg)] = (_Float16)(v * sg);
                }
            }
        __syncthreads();
    }

    // ---------------- out = t3 @ w_out  (O=1, VALU dot) ----------------
    {
        int el    = tid >> 1;
        int half  = tid & 1;
        int cbase = half * 128;
        float sum = 0.f;
        #pragma unroll
        for (int cc = 0; cc < 128; cc += 8) {
            int c = cbase + cc;
            f16x8 tv = *(const f16x8*)&tbuf[swz(el, c)];
            #pragma unroll
            for (int jj = 0; jj < 8; ++jj)
                sum += (float)tv[jj] * w_out[c + jj];
        }
        sum += __shfl_xor(sum, 1);
        if (half == 0) out[e0 + el] = sum;
    }
}

extern "C" void kernel_launch(void* const* d_in, const int* in_sizes, int n_in,
                              void* d_out, int out_size, void* d_ws, size_t ws_size,
                              hipStream_t stream)
{
    const float* x     = (const float*)d_in[0];
    const float* rbf   = (const float*)d_in[1];
    const int*   nidx  = (const int*)d_in[2];
    const float* w_rbf = (const float*)d_in[3];
    const float* w_up  = (const float*)d_in[4];
    const float* Ws    = (const float*)d_in[5];
    const float* bs    = (const float*)d_in[6];
    const float* w_out = (const float*)d_in[7];

    float* xspe = (float*)d_out;                       // [N,128]
    float* outp = xspe + (size_t)N_NODES * H_DIM;      // [E,1]
    _Float16* wf = (_Float16*)d_ws;                    // 448 KB used

    // zero the scatter target (d_out is poisoned before every launch)
    hipMemsetAsync(d_out, 0, (size_t)N_NODES * H_DIM * sizeof(float), stream);
    prep_weights<<<dim3(896), dim3(256), 0, stream>>>(w_up, Ws, wf);
    fused_main<<<dim3(NBLK), dim3(256), 0, stream>>>(x, rbf, nidx, w_rbf, bs,
                                                     w_out, wf, xspe, outp);
}

// Round 3
// 957.364 us; speedup vs baseline: 1.9625x; 1.9625x over previous
//
#include <hip/hip_runtime.h>

#define E_TOT   400000
#define N_NODES 50000
#define H_DIM   128
#define D_DIM   256
#define TE      128                 // edges per block
#define NBLK    (E_TOT / TE)        // 3125
#define NSCAN_BLK 196               // ceil(50000/256)

typedef _Float16 f16x8 __attribute__((ext_vector_type(8)));
typedef float    f32x2 __attribute__((ext_vector_type(2)));
typedef float    f32x4 __attribute__((ext_vector_type(4)));
typedef float    f32x16 __attribute__((ext_vector_type(16)));

// swizzled f16 index into the [128][256] LDS tile: XOR row bits into the
// 16B-chunk bits of the column so stride-512B column reads spread across banks
__device__ __forceinline__ int swz(int row, int col) {
    return row * 256 + (col ^ ((row & 7) << 3));
}

__device__ __forceinline__ f32x16 zero16() {
    f32x16 z = {0.f,0.f,0.f,0.f,0.f,0.f,0.f,0.f,0.f,0.f,0.f,0.f,0.f,0.f,0.f,0.f};
    return z;
}

// ---------------------------------------------------------------------------
// Prep: repack w_up [128][256] and Ws [3][256][256] (fp32, [in][out]) into
// fragment-ordered f16: elem(lane,j) = W[kb*16 + 8*(lane>>5)+j][nb*32+(lane&31)]
// ---------------------------------------------------------------------------
__global__ void prep_weights(const float* __restrict__ w_up,
                             const float* __restrict__ Ws,
                             _Float16* __restrict__ wf)
{
    int t = blockIdx.x * 256 + threadIdx.x;    // 0 .. 229375
    int j    = t & 7;
    int lane = (t >> 3) & 63;
    int frag = t >> 9;
    int khalf = (lane >> 5) << 3;
    int col31 = lane & 31;
    float v;
    if (frag < 64) {                           // w_up: K=128 -> kb 0..7
        int nb = frag >> 3, kb = frag & 7;
        v = w_up[(kb * 16 + khalf + j) * 256 + nb * 32 + col31];
    } else {                                   // Ws: K=256 -> kb 0..15
        int f2 = frag - 64;
        int layer = f2 >> 7;
        int fl = f2 & 127;
        int nb = fl >> 4, kb = fl & 15;
        v = Ws[layer * 65536 + (kb * 16 + khalf + j) * 256 + nb * 32 + col31];
    }
    wf[t] = (_Float16)v;
}

// ---------------------------------------------------------------------------
// CSR build: histogram -> 2-level exclusive scan -> scatter edge ids
// ---------------------------------------------------------------------------
__global__ void k_hist(const int* __restrict__ ni, int* __restrict__ counts) {
    int e = blockIdx.x * 256 + threadIdx.x;
    if (e < E_TOT) atomicAdd(&counts[ni[e]], 1);
}

__global__ void k_scan_block(const int* __restrict__ counts,
                             int* __restrict__ starts, int* __restrict__ bsum) {
    __shared__ int s[256];
    int tid = threadIdx.x;
    int idx = blockIdx.x * 256 + tid;
    int v = (idx < N_NODES) ? counts[idx] : 0;
    s[tid] = v; __syncthreads();
    #pragma unroll
    for (int off = 1; off < 256; off <<= 1) {
        int t = (tid >= off) ? s[tid - off] : 0; __syncthreads();
        s[tid] += t; __syncthreads();
    }
    if (idx < N_NODES) starts[idx] = s[tid] - v;       // local exclusive
    if (tid == 255) bsum[blockIdx.x] = s[255];         // block total
}

__global__ void k_scan_top(int* __restrict__ bsum) {
    __shared__ int s[256];
    int tid = threadIdx.x;
    int v = (tid < NSCAN_BLK) ? bsum[tid] : 0;
    s[tid] = v; __syncthreads();
    #pragma unroll
    for (int off = 1; off < 256; off <<= 1) {
        int t = (tid >= off) ? s[tid - off] : 0; __syncthreads();
        s[tid] += t; __syncthreads();
    }
    if (tid < NSCAN_BLK) bsum[tid] = s[tid] - v;       // exclusive
}

__global__ void k_scan_add(int* __restrict__ starts, const int* __restrict__ bsum,
                           int* __restrict__ cursor) {
    int idx = blockIdx.x * 256 + threadIdx.x;
    if (idx < N_NODES) {
        int v = starts[idx] + bsum[blockIdx.x];
        starts[idx] = v;
        cursor[idx] = v;
    }
    if (idx == 0) starts[N_NODES] = E_TOT;
}

__global__ void k_scatter(const int* __restrict__ ni, int* __restrict__ cursor,
                          int* __restrict__ eid) {
    int e = blockIdx.x * 256 + threadIdx.x;
    if (e < E_TOT) {
        int slot = atomicAdd(&cursor[ni[e]], 1);
        eid[slot] = e;
    }
}

// ---------------------------------------------------------------------------
// Gather: one wave per node; recompute h = (rbf@w_rbf)*x in fp32 and sum.
// Writes every x_spe row exactly once (no atomics, no memset needed).
// ---------------------------------------------------------------------------
__global__ __launch_bounds__(256)
void k_gather(const float* __restrict__ x, const float* __restrict__ rbf,
              const float* __restrict__ w_rbf, const int* __restrict__ starts,
              const int* __restrict__ eid, float* __restrict__ xspe)
{
    int wid  = threadIdx.x >> 6;
    int l    = threadIdx.x & 63;
    int node = blockIdx.x * 4 + wid;       // 12500 * 4 = 50000 exact
    int c0   = l * 2;

    float wr[6][2];
    #pragma unroll
    for (int r = 0; r < 6; ++r) {
        wr[r][0] = w_rbf[r * 128 + c0];
        wr[r][1] = w_rbf[r * 128 + c0 + 1];
    }

    int kb = starts[node], ke = starts[node + 1];
    float a0 = 0.f, a1 = 0.f;
    for (int k = kb; k < ke; ++k) {
        int e = eid[k];
        float rb[6];
        #pragma unroll
        for (int r = 0; r < 6; ++r) rb[r] = rbf[(size_t)e * 6 + r];
        f32x2 xv = *(const f32x2*)(x + (size_t)e * 128 + c0);
        float s0 = 0.f, s1 = 0.f;
        #pragma unroll
        for (int r = 0; r < 6; ++r) { s0 += rb[r] * wr[r][0]; s1 += rb[r] * wr[r][1]; }
        a0 += s0 * xv[0];
        a1 += s1 * xv[1];
    }
    f32x2 o = {a0, a1};
    *(f32x2*)(xspe + (size_t)node * 128 + c0) = o;
}

// ---------------------------------------------------------------------------
// Fused edge kernel: h tile -> f16 MFMA tower -> out (no atomics now)
// ---------------------------------------------------------------------------
__global__ __launch_bounds__(256, 2)
void fused_main(const float* __restrict__ x,
                const float* __restrict__ rbf,
                const float* __restrict__ w_rbf,
                const float* __restrict__ bs,
                const float* __restrict__ w_out,
                const _Float16* __restrict__ wf,
                float* __restrict__ out)
{
    __shared__ __align__(16) _Float16 tbuf[TE * 256];   // 64 KB
    const int tid = threadIdx.x;
    const int e0  = blockIdx.x * TE;

    // ---------------- stage 1: h tile (f16) ----------------
    {
        const int cg = tid & 15;
        const int eg = tid >> 4;
        const int c0 = cg << 3;
        float wr[6][8];
        #pragma unroll
        for (int r = 0; r < 6; ++r)
            #pragma unroll
            for (int c = 0; c < 8; ++c)
                wr[r][c] = w_rbf[r * 128 + c0 + c];

        #pragma unroll
        for (int ee = 0; ee < 8; ++ee) {
            int el = eg * 8 + ee;
            int e  = e0 + el;
            float rb[6];
            #pragma unroll
            for (int r = 0; r < 6; ++r) rb[r] = rbf[(size_t)e * 6 + r];
            f32x4 xv0 = *(const f32x4*)(x + (size_t)e * 128 + c0);
            f32x4 xv1 = *(const f32x4*)(x + (size_t)e * 128 + c0 + 4);
            f16x8 hv;
            #pragma unroll
            for (int c = 0; c < 8; ++c) {
                float s = 0.f;
                #pragma unroll
                for (int r = 0; r < 6; ++r) s += rb[r] * wr[r][c];
                float xvv = (c < 4) ? xv0[c] : xv1[c - 4];
                hv[c] = (_Float16)(s * xvv);
            }
            *(f16x8*)&tbuf[swz(el, c0)] = hv;
        }
    }
    __syncthreads();

    const int l    = tid & 63;
    const int w    = tid >> 6;
    const int rs   = w >> 1;
    const int cs   = w & 1;
    const int l31  = l & 31;
    const int lh   = l >> 5;
    const int khalf = lh << 3;

    const f16x8* __restrict__ wupf = (const f16x8*)wf;
    const f16x8* __restrict__ wlf  = ((const f16x8*)wf) + 4096;

    f32x16 acc[2][4];

    // ---------------- GEMM1: t1 = h @ w_up (K=128) ----------------
    #pragma unroll
    for (int rf = 0; rf < 2; ++rf)
        #pragma unroll
        for (int nf = 0; nf < 4; ++nf) acc[rf][nf] = zero16();

    for (int kb = 0; kb < 8; ++kb) {
        int k0 = kb * 16 + khalf;
        f16x8 a0 = *(const f16x8*)&tbuf[swz(rs * 64 +  0 + l31, k0)];
        f16x8 a1 = *(const f16x8*)&tbuf[swz(rs * 64 + 32 + l31, k0)];
        f16x8 b[4];
        #pragma unroll
        for (int nf = 0; nf < 4; ++nf)
            b[nf] = wupf[((cs * 4 + nf) * 8 + kb) * 64 + l];
        #pragma unroll
        for (int nf = 0; nf < 4; ++nf) {
            acc[0][nf] = __builtin_amdgcn_mfma_f32_32x32x16_f16(a0, b[nf], acc[0][nf], 0, 0, 0);
            acc[1][nf] = __builtin_amdgcn_mfma_f32_32x32x16_f16(a1, b[nf], acc[1][nf], 0, 0, 0);
        }
    }
    __syncthreads();
    #pragma unroll
    for (int rf = 0; rf < 2; ++rf)
        #pragma unroll
        for (int nf = 0; nf < 4; ++nf) {
            int colg = cs * 128 + nf * 32 + l31;
            #pragma unroll
            for (int r = 0; r < 16; ++r) {
                int rowl = (r & 3) + 8 * (r >> 2) + 4 * lh;   // C/D layout m74/m101
                int row  = rs * 64 + rf * 32 + rowl;
                tbuf[swz(row, colg)] = (_Float16)acc[rf][nf][r];
            }
        }
    __syncthreads();

    // ---------------- 3x: t = silu(t @ W + b), K=256 ----------------
    for (int layer = 0; layer < 3; ++layer) {
        const f16x8* wl = wlf + layer * 8192;
        float bias[4];
        #pragma unroll
        for (int nf = 0; nf < 4; ++nf)
            bias[nf] = bs[layer * 256 + cs * 128 + nf * 32 + l31];
        #pragma unroll
        for (int rf = 0; rf < 2; ++rf)
            #pragma unroll
            for (int nf = 0; nf < 4; ++nf) acc[rf][nf] = zero16();

        for (int kb = 0; kb < 16; ++kb) {
            int k0 = kb * 16 + khalf;
            f16x8 a0 = *(const f16x8*)&tbuf[swz(rs * 64 +  0 + l31, k0)];
            f16x8 a1 = *(const f16x8*)&tbuf[swz(rs * 64 + 32 + l31, k0)];
            f16x8 b[4];
            #pragma unroll
            for (int nf = 0; nf < 4; ++nf)
                b[nf] = wl[((cs * 4 + nf) * 16 + kb) * 64 + l];
            #pragma unroll
            for (int nf = 0; nf < 4; ++nf) {
                acc[0][nf] = __builtin_amdgcn_mfma_f32_32x32x16_f16(a0, b[nf], acc[0][nf], 0, 0, 0);
                acc[1][nf] = __builtin_amdgcn_mfma_f32_32x32x16_f16(a1, b[nf], acc[1][nf], 0, 0, 0);
            }
        }
        __syncthreads();
        #pragma unroll
        for (int rf = 0; rf < 2; ++rf)
            #pragma unroll
            for (int nf = 0; nf < 4; ++nf) {
                int colg = cs * 128 + nf * 32 + l31;
                #pragma unroll
                for (int r = 0; r < 16; ++r) {
                    int rowl = (r & 3) + 8 * (r >> 2) + 4 * lh;
                    int row  = rs * 64 + rf * 32 + rowl;
                    float v = acc[rf][nf][r] + bias[nf];
                    float sg = __builtin_amdgcn_rcpf(1.0f + __expf(-v));
                    tbuf[swz(row, colg)] = (_Float16)(v * sg);
                }
            }
        __syncthreads();
    }

    // ---------------- out = t3 @ w_out  (O=1, VALU dot) ----------------
    {
        int el    = tid >> 1;
        int half  = tid & 1;
        int cbase = half * 128;
        float sum = 0.f;
        #pragma unroll
        for (int cc = 0; cc < 128; cc += 8) {
            int c = cbase + cc;
            f16x8 tv = *(const f16x8*)&tbuf[swz(el, c)];
            #pragma unroll
            for (int jj = 0; jj < 8; ++jj)
                sum += (float)tv[jj] * w_out[c + jj];
        }
        sum += __shfl_xor(sum, 1);
        if (half == 0) out[e0 + el] = sum;
    }
}

extern "C" void kernel_launch(void* const* d_in, const int* in_sizes, int n_in,
                              void* d_out, int out_size, void* d_ws, size_t ws_size,
                              hipStream_t stream)
{
    const float* x     = (const float*)d_in[0];
    const float* rbf   = (const float*)d_in[1];
    const int*   nidx  = (const int*)d_in[2];
    const float* w_rbf = (const float*)d_in[3];
    const float* w_up  = (const float*)d_in[4];
    const float* Ws    = (const float*)d_in[5];
    const float* bs    = (const float*)d_in[6];
    const float* w_out = (const float*)d_in[7];

    float* xspe = (float*)d_out;                       // [N,128]
    float* outp = xspe + (size_t)N_NODES * H_DIM;      // [E,1]

    char* ws = (char*)d_ws;
    _Float16* wf   = (_Float16*)ws;                    // 458752 B
    int* counts    = (int*)(ws + 0x080000);            // 50000
    int* starts    = (int*)(ws + 0x0C0000);            // 50001
    int* cursor    = (int*)(ws + 0x100000);            // 50000
    int* bsum      = (int*)(ws + 0x140000);            // 196
    int* eid       = (int*)(ws + 0x150000);            // 400000

    hipMemsetAsync(counts, 0, N_NODES * sizeof(int), stream);
    prep_weights<<<dim3(896), dim3(256), 0, stream>>>(w_up, Ws, wf);
    k_hist      <<<dim3(1563), dim3(256), 0, stream>>>(nidx, counts);
    k_scan_block<<<dim3(NSCAN_BLK), dim3(256), 0, stream>>>(counts, starts, bsum);
    k_scan_top  <<<dim3(1), dim3(256), 0, stream>>>(bsum);
    k_scan_add  <<<dim3(NSCAN_BLK), dim3(256), 0, stream>>>(starts, bsum, cursor);
    k_scatter   <<<dim3(1563), dim3(256), 0, stream>>>(nidx, cursor, eid);
    fused_main  <<<dim3(NBLK), dim3(256), 0, stream>>>(x, rbf, w_rbf, bs, w_out, wf, outp);
    k_gather    <<<dim3(12500), dim3(256), 0, stream>>>(x, rbf, w_rbf, starts, eid, xspe);
}

// Round 4
// 702.005 us; speedup vs baseline: 2.6764x; 1.3638x over previous
//
#include <hip/hip_runtime.h>

#define E_TOT   400000
#define N_NODES 50000
#define H_DIM   128
#define D_DIM   256
#define TE      128                 // edges per block
#define NBLK    (E_TOT / TE)        // 3125
#define NSCAN_BLK 196               // ceil(50000/256)

typedef _Float16 f16x8 __attribute__((ext_vector_type(8)));
typedef float    f32x2 __attribute__((ext_vector_type(2)));
typedef float    f32x4 __attribute__((ext_vector_type(4)));
typedef float    f32x16 __attribute__((ext_vector_type(16)));

// swizzled f16 index into the [128][256] LDS tile: XOR row bits into the
// 16B-chunk bits of the column so stride-512B column reads spread across banks
__device__ __forceinline__ int swz(int row, int col) {
    return row * 256 + (col ^ ((row & 7) << 3));
}

__device__ __forceinline__ f32x16 zero16() {
    f32x16 z = {0.f,0.f,0.f,0.f,0.f,0.f,0.f,0.f,0.f,0.f,0.f,0.f,0.f,0.f,0.f,0.f};
    return z;
}

// ---------------------------------------------------------------------------
// Prep: repack w_up [128][256] and Ws [3][256][256] (fp32, [in][out]) into
// fragment-ordered f16: elem(lane,j) = W[kb*16 + 8*(lane>>5)+j][nb*32+(lane&31)]
// ---------------------------------------------------------------------------
__global__ void prep_weights(const float* __restrict__ w_up,
                             const float* __restrict__ Ws,
                             _Float16* __restrict__ wf)
{
    int t = blockIdx.x * 256 + threadIdx.x;    // 0 .. 229375
    int j    = t & 7;
    int lane = (t >> 3) & 63;
    int frag = t >> 9;
    int khalf = (lane >> 5) << 3;
    int col31 = lane & 31;
    float v;
    if (frag < 64) {                           // w_up: K=128 -> kb 0..7
        int nb = frag >> 3, kb = frag & 7;
        v = w_up[(kb * 16 + khalf + j) * 256 + nb * 32 + col31];
    } else {                                   // Ws: K=256 -> kb 0..15
        int f2 = frag - 64;
        int layer = f2 >> 7;
        int fl = f2 & 127;
        int nb = fl >> 4, kb = fl & 15;
        v = Ws[layer * 65536 + (kb * 16 + khalf + j) * 256 + nb * 32 + col31];
    }
    wf[t] = (_Float16)v;
}

// ---------------------------------------------------------------------------
// CSR build: histogram -> 2-level exclusive scan -> scatter edge ids
// ---------------------------------------------------------------------------
__global__ void k_hist(const int* __restrict__ ni, int* __restrict__ counts) {
    int e = blockIdx.x * 256 + threadIdx.x;
    if (e < E_TOT) atomicAdd(&counts[ni[e]], 1);
}

__global__ void k_scan_block(const int* __restrict__ counts,
                             int* __restrict__ starts, int* __restrict__ bsum) {
    __shared__ int s[256];
    int tid = threadIdx.x;
    int idx = blockIdx.x * 256 + tid;
    int v = (idx < N_NODES) ? counts[idx] : 0;
    s[tid] = v; __syncthreads();
    #pragma unroll
    for (int off = 1; off < 256; off <<= 1) {
        int t = (tid >= off) ? s[tid - off] : 0; __syncthreads();
        s[tid] += t; __syncthreads();
    }
    if (idx < N_NODES) starts[idx] = s[tid] - v;       // local exclusive
    if (tid == 255) bsum[blockIdx.x] = s[255];         // block total
}

__global__ void k_scan_top(int* __restrict__ bsum) {
    __shared__ int s[256];
    int tid = threadIdx.x;
    int v = (tid < NSCAN_BLK) ? bsum[tid] : 0;
    s[tid] = v; __syncthreads();
    #pragma unroll
    for (int off = 1; off < 256; off <<= 1) {
        int t = (tid >= off) ? s[tid - off] : 0; __syncthreads();
        s[tid] += t; __syncthreads();
    }
    if (tid < NSCAN_BLK) bsum[tid] = s[tid] - v;       // exclusive
}

__global__ void k_scan_add(int* __restrict__ starts, const int* __restrict__ bsum,
                           int* __restrict__ cursor) {
    int idx = blockIdx.x * 256 + threadIdx.x;
    if (idx < N_NODES) {
        int v = starts[idx] + bsum[blockIdx.x];
        starts[idx] = v;
        cursor[idx] = v;
    }
    if (idx == 0) starts[N_NODES] = E_TOT;
}

__global__ void k_scatter(const int* __restrict__ ni, int* __restrict__ cursor,
                          int* __restrict__ eid) {
    int e = blockIdx.x * 256 + threadIdx.x;
    if (e < E_TOT) {
        int slot = atomicAdd(&cursor[ni[e]], 1);
        eid[slot] = e;
    }
}

// ---------------------------------------------------------------------------
// Gather: one wave per node; recompute h = (rbf@w_rbf)*x in fp32 and sum.
// Writes every x_spe row exactly once (no atomics, no memset needed).
// ---------------------------------------------------------------------------
__global__ __launch_bounds__(256)
void k_gather(const float* __restrict__ x, const float* __restrict__ rbf,
              const float* __restrict__ w_rbf, const int* __restrict__ starts,
              const int* __restrict__ eid, float* __restrict__ xspe)
{
    int wid  = threadIdx.x >> 6;
    int l    = threadIdx.x & 63;
    int node = blockIdx.x * 4 + wid;       // 12500 * 4 = 50000 exact
    int c0   = l * 2;

    float wr[6][2];
    #pragma unroll
    for (int r = 0; r < 6; ++r) {
        wr[r][0] = w_rbf[r * 128 + c0];
        wr[r][1] = w_rbf[r * 128 + c0 + 1];
    }

    int kb = starts[node], ke = starts[node + 1];
    float a0 = 0.f, a1 = 0.f;
    for (int k = kb; k < ke; ++k) {
        int e = eid[k];
        float rb[6];
        #pragma unroll
        for (int r = 0; r < 6; ++r) rb[r] = rbf[(size_t)e * 6 + r];
        f32x2 xv = *(const f32x2*)(x + (size_t)e * 128 + c0);
        float s0 = 0.f, s1 = 0.f;
        #pragma unroll
        for (int r = 0; r < 6; ++r) { s0 += rb[r] * wr[r][0]; s1 += rb[r] * wr[r][1]; }
        a0 += s0 * xv[0];
        a1 += s1 * xv[1];
    }
    f32x2 o = {a0, a1};
    *(f32x2*)(xspe + (size_t)node * 128 + c0) = o;
}

// ---------------------------------------------------------------------------
// Fused edge kernel: h tile -> f16 MFMA tower -> out
// 512 threads / 8 waves; wave (rs,cs) owns rows rs*64..+64, cols cs*64..+64
// acc = 2x2 frags of 32x32 = 64 f32/lane -> fits 4 waves/SIMD (no spills)
// ---------------------------------------------------------------------------
__global__ __launch_bounds__(512, 4)
void fused_main(const float* __restrict__ x,
                const float* __restrict__ rbf,
                const float* __restrict__ w_rbf,
                const float* __restrict__ bs,
                const float* __restrict__ w_out,
                const _Float16* __restrict__ wf,
                float* __restrict__ out)
{
    __shared__ __align__(16) _Float16 tbuf[TE * 256];   // 64 KB
    const int tid = threadIdx.x;
    const int e0  = blockIdx.x * TE;

    // ---------------- stage 1: h tile (f16) ----------------
    {
        const int cg = tid & 15;        // col group: cols 8*cg..+7
        const int eg = tid >> 4;        // 0..31, 4 edges each
        const int c0 = cg << 3;
        float wr[6][8];
        #pragma unroll
        for (int r = 0; r < 6; ++r)
            #pragma unroll
            for (int c = 0; c < 8; ++c)
                wr[r][c] = w_rbf[r * 128 + c0 + c];

        #pragma unroll
        for (int ee = 0; ee < 4; ++ee) {
            int el = eg * 4 + ee;
            int e  = e0 + el;
            float rb[6];
            #pragma unroll
            for (int r = 0; r < 6; ++r) rb[r] = rbf[(size_t)e * 6 + r];
            f32x4 xv0 = *(const f32x4*)(x + (size_t)e * 128 + c0);
            f32x4 xv1 = *(const f32x4*)(x + (size_t)e * 128 + c0 + 4);
            f16x8 hv;
            #pragma unroll
            for (int c = 0; c < 8; ++c) {
                float s = 0.f;
                #pragma unroll
                for (int r = 0; r < 6; ++r) s += rb[r] * wr[r][c];
                float xvv = (c < 4) ? xv0[c] : xv1[c - 4];
                hv[c] = (_Float16)(s * xvv);
            }
            *(f16x8*)&tbuf[swz(el, c0)] = hv;
        }
    }
    __syncthreads();

    const int l    = tid & 63;
    const int w    = tid >> 6;          // 0..7
    const int rs   = w >> 2;            // row half 0/1
    const int cs   = w & 3;             // col quarter 0..3
    const int l31  = l & 31;
    const int lh   = l >> 5;
    const int khalf = lh << 3;
    const int r0   = rs * 64;

    const f16x8* __restrict__ wupf = (const f16x8*)wf;
    const f16x8* __restrict__ wlf  = ((const f16x8*)wf) + 4096;

    f32x16 acc00, acc01, acc10, acc11;   // [rf][nf]

    // ---------------- GEMM1: t1 = h @ w_up (K=128) ----------------
    acc00 = acc01 = acc10 = acc11 = zero16();
    {
        f16x8 bc0 = wupf[((cs * 2 + 0) * 8 + 0) * 64 + l];
        f16x8 bc1 = wupf[((cs * 2 + 1) * 8 + 0) * 64 + l];
        #pragma unroll
        for (int kb = 0; kb < 8; ++kb) {
            f16x8 bn0, bn1;
            if (kb < 7) {
                bn0 = wupf[((cs * 2 + 0) * 8 + kb + 1) * 64 + l];
                bn1 = wupf[((cs * 2 + 1) * 8 + kb + 1) * 64 + l];
            }
            int k0 = kb * 16 + khalf;
            f16x8 a0 = *(const f16x8*)&tbuf[swz(r0 +  0 + l31, k0)];
            f16x8 a1 = *(const f16x8*)&tbuf[swz(r0 + 32 + l31, k0)];
            acc00 = __builtin_amdgcn_mfma_f32_32x32x16_f16(a0, bc0, acc00, 0, 0, 0);
            acc10 = __builtin_amdgcn_mfma_f32_32x32x16_f16(a1, bc0, acc10, 0, 0, 0);
            acc01 = __builtin_amdgcn_mfma_f32_32x32x16_f16(a0, bc1, acc01, 0, 0, 0);
            acc11 = __builtin_amdgcn_mfma_f32_32x32x16_f16(a1, bc1, acc11, 0, 0, 0);
            bc0 = bn0; bc1 = bn1;
        }
    }
    __syncthreads();
    {
        int cg0 = cs * 64 + l31;
        #pragma unroll
        for (int r = 0; r < 16; ++r) {
            int rowl = (r & 3) + 8 * (r >> 2) + 4 * lh;   // C/D layout m74/m101
            tbuf[swz(r0 +  0 + rowl, cg0)]      = (_Float16)acc00[r];
            tbuf[swz(r0 +  0 + rowl, cg0 + 32)] = (_Float16)acc01[r];
            tbuf[swz(r0 + 32 + rowl, cg0)]      = (_Float16)acc10[r];
            tbuf[swz(r0 + 32 + rowl, cg0 + 32)] = (_Float16)acc11[r];
        }
    }
    __syncthreads();

    // ---------------- 3x: t = silu(t @ W + b), K=256 ----------------
    for (int layer = 0; layer < 3; ++layer) {
        const f16x8* wl = wlf + layer * 8192;
        float bias0 = bs[layer * 256 + cs * 64 + l31];
        float bias1 = bs[layer * 256 + cs * 64 + 32 + l31];
        acc00 = acc01 = acc10 = acc11 = zero16();

        f16x8 bc0 = wl[((cs * 2 + 0) * 16 + 0) * 64 + l];
        f16x8 bc1 = wl[((cs * 2 + 1) * 16 + 0) * 64 + l];
        #pragma unroll
        for (int kb = 0; kb < 16; ++kb) {
            f16x8 bn0, bn1;
            if (kb < 15) {
                bn0 = wl[((cs * 2 + 0) * 16 + kb + 1) * 64 + l];
                bn1 = wl[((cs * 2 + 1) * 16 + kb + 1) * 64 + l];
            }
            int k0 = kb * 16 + khalf;
            f16x8 a0 = *(const f16x8*)&tbuf[swz(r0 +  0 + l31, k0)];
            f16x8 a1 = *(const f16x8*)&tbuf[swz(r0 + 32 + l31, k0)];
            acc00 = __builtin_amdgcn_mfma_f32_32x32x16_f16(a0, bc0, acc00, 0, 0, 0);
            acc10 = __builtin_amdgcn_mfma_f32_32x32x16_f16(a1, bc0, acc10, 0, 0, 0);
            acc01 = __builtin_amdgcn_mfma_f32_32x32x16_f16(a0, bc1, acc01, 0, 0, 0);
            acc11 = __builtin_amdgcn_mfma_f32_32x32x16_f16(a1, bc1, acc11, 0, 0, 0);
            bc0 = bn0; bc1 = bn1;
        }
        __syncthreads();
        {
            int cg0 = cs * 64 + l31;
            #pragma unroll
            for (int r = 0; r < 16; ++r) {
                int rowl = (r & 3) + 8 * (r >> 2) + 4 * lh;
                float v00 = acc00[r] + bias0;
                float v01 = acc01[r] + bias1;
                float v10 = acc10[r] + bias0;
                float v11 = acc11[r] + bias1;
                float s00 = __builtin_amdgcn_rcpf(1.0f + __expf(-v00));
                float s01 = __builtin_amdgcn_rcpf(1.0f + __expf(-v01));
                float s10 = __builtin_amdgcn_rcpf(1.0f + __expf(-v10));
                float s11 = __builtin_amdgcn_rcpf(1.0f + __expf(-v11));
                tbuf[swz(r0 +  0 + rowl, cg0)]      = (_Float16)(v00 * s00);
                tbuf[swz(r0 +  0 + rowl, cg0 + 32)] = (_Float16)(v01 * s01);
                tbuf[swz(r0 + 32 + rowl, cg0)]      = (_Float16)(v10 * s10);
                tbuf[swz(r0 + 32 + rowl, cg0 + 32)] = (_Float16)(v11 * s11);
            }
        }
        __syncthreads();
    }

    // ---------------- out = t3 @ w_out  (O=1, VALU dot) ----------------
    {
        int el = tid >> 2;              // 0..127
        int q  = tid & 3;               // col quarter
        int cbase = q * 64;
        float sum = 0.f;
        #pragma unroll
        for (int cc = 0; cc < 64; cc += 8) {
            int c = cbase + cc;
            f16x8 tv = *(const f16x8*)&tbuf[swz(el, c)];
            #pragma unroll
            for (int jj = 0; jj < 8; ++jj)
                sum += (float)tv[jj] * w_out[c + jj];
        }
        sum += __shfl_xor(sum, 1);
        sum += __shfl_xor(sum, 2);
        if (q == 0) out[e0 + el] = sum;
    }
}

extern "C" void kernel_launch(void* const* d_in, const int* in_sizes, int n_in,
                              void* d_out, int out_size, void* d_ws, size_t ws_size,
                              hipStream_t stream)
{
    const float* x     = (const float*)d_in[0];
    const float* rbf   = (const float*)d_in[1];
    const int*   nidx  = (const int*)d_in[2];
    const float* w_rbf = (const float*)d_in[3];
    const float* w_up  = (const float*)d_in[4];
    const float* Ws    = (const float*)d_in[5];
    const float* bs    = (const float*)d_in[6];
    const float* w_out = (const float*)d_in[7];

    float* xspe = (float*)d_out;                       // [N,128]
    float* outp = xspe + (size_t)N_NODES * H_DIM;      // [E,1]

    char* ws = (char*)d_ws;
    _Float16* wf   = (_Float16*)ws;                    // 458752 B
    int* counts    = (int*)(ws + 0x080000);            // 50000
    int* starts    = (int*)(ws + 0x0C0000);            // 50001
    int* cursor    = (int*)(ws + 0x100000);            // 50000
    int* bsum      = (int*)(ws + 0x140000);            // 196
    int* eid       = (int*)(ws + 0x150000);            // 400000

    hipMemsetAsync(counts, 0, N_NODES * sizeof(int), stream);
    prep_weights<<<dim3(896), dim3(256), 0, stream>>>(w_up, Ws, wf);
    k_hist      <<<dim3(1563), dim3(256), 0, stream>>>(nidx, counts);
    k_scan_block<<<dim3(NSCAN_BLK), dim3(256), 0, stream>>>(counts, starts, bsum);
    k_scan_top  <<<dim3(1), dim3(256), 0, stream>>>(bsum);
    k_scan_add  <<<dim3(NSCAN_BLK), dim3(256), 0, stream>>>(starts, bsum, cursor);
    k_scatter   <<<dim3(1563), dim3(256), 0, stream>>>(nidx, cursor, eid);
    fused_main  <<<dim3(NBLK), dim3(512), 0, stream>>>(x, rbf, w_rbf, bs, w_out, wf, outp);
    k_gather    <<<dim3(12500), dim3(256), 0, stream>>>(x, rbf, w_rbf, starts, eid, xspe);
}